// Round 3
// baseline (891.135 us; speedup 1.0000x reference)
//
#include <hip/hip_runtime.h>

// Problem constants
#define NSAMP 262144
#define CCLS 128
#define DDIM 256
#define EPSF 1e-8f

// ws byte offsets (16B-aligned where vector-accessed)
#define OFF_COUNTS   0u          // 128 * u32
#define OFF_G        2048u       // 128x128 f32
#define OFF_W        67584u      // 128x128 f32 (G^-1)
#define OFF_TT       133120u     // 256x128 f32 (T transposed)
#define OFF_MRAW     264192u     // 128x256 f32 (class means, unprojected)
#define OFF_B        395264u     // 128x128 f32 (Mraw @ T^T)
#define OFF_ZT       460800u     // 128x128 f32 (W @ B^T)
#define OFF_M        526336u     // 128x128 f32 (B W B^T)
#define OFF_BIG      1644288u    // partial slabs, 32768 f32 each
#define SLAB_FLOATS  32768

// ---------------------------------------------------------------------------
// KG: 4 blocks. Block g computes rows [32g,32g+32) of G = T*T^T and writes
//     T^T chunk g. (verbatim from verified round-1 code)
// ---------------------------------------------------------------------------
extern "C" __global__ __launch_bounds__(1024)
void kg_gram(const float* __restrict__ T, char* __restrict__ ws)
{
    __shared__ float Tl[64][132];
    const int g = blockIdx.x, tid = threadIdx.x;
    float* Tt = (float*)(ws + OFF_TT);
    float* G  = (float*)(ws + OFF_G);
    float a0[8], a1[8];
    #pragma unroll
    for (int j = 0; j < 8; ++j) { a0[j] = 0.f; a1[j] = 0.f; }
    const int Lr = 2 * (tid >> 4);
    const int c0 = 8 * (tid & 15);
    for (int ch = 0; ch < 4; ++ch) {
        for (int i = tid; i < 8192; i += 1024) {
            int cc = i >> 6, dd = i & 63;
            Tl[dd][cc] = T[cc * 256 + ch * 64 + dd];
        }
        __syncthreads();
        if (g == ch) {
            for (int i = tid; i < 8192; i += 1024) {
                int c2 = i & 127, d2 = i >> 7;
                Tt[(ch * 64 + d2) * 128 + c2] = Tl[d2][c2];
            }
        }
        if (tid < 256) {
            for (int dd = 0; dd < 64; ++dd) {
                float r0 = Tl[dd][32 * g + Lr];
                float r1 = Tl[dd][32 * g + Lr + 1];
                float cv[8];
                *(float4*)&cv[0] = *(const float4*)&Tl[dd][c0];
                *(float4*)&cv[4] = *(const float4*)&Tl[dd][c0 + 4];
                #pragma unroll
                for (int j = 0; j < 8; ++j) { a0[j] += r0 * cv[j]; a1[j] += r1 * cv[j]; }
            }
        }
        __syncthreads();
    }
    if (tid < 256) {
        int gr = 32 * g + Lr;
        *(float4*)&G[gr * 128 + c0]           = make_float4(a0[0], a0[1], a0[2], a0[3]);
        *(float4*)&G[gr * 128 + c0 + 4]       = make_float4(a0[4], a0[5], a0[6], a0[7]);
        *(float4*)&G[(gr + 1) * 128 + c0]     = make_float4(a1[0], a1[1], a1[2], a1[3]);
        *(float4*)&G[(gr + 1) * 128 + c0 + 4] = make_float4(a1[4], a1[5], a1[6], a1[7]);
    }
}

// ---------------------------------------------------------------------------
// KA: fused argmax + gated segment-sum. 256 blocks x 1024 threads.
//     Wave w owns samples [b*1024 + 64w, +64). Gated-only processing via
//     ballot bit-scan, 2-deep software pipeline. LDS acc[128][256] f32 with
//     permuted dim layout (d = 4L+j stored at slot j*64+L -> conflict-free
//     ds_add). Flush: own slab store (nSlab==256) or f32 atomics into slab b%nSlab.
// ---------------------------------------------------------------------------
extern "C" __global__ __launch_bounds__(1024)
void ka_fused(const float* __restrict__ logits, const float* __restrict__ img,
              const void* __restrict__ mask, char* __restrict__ ws, int nSlab)
{
    __shared__ float acc[CCLS][DDIM];   // 128 KB
    __shared__ int cnts[CCLS];
    __shared__ int sIsBool;
    const int b = blockIdx.x, tid = threadIdx.x;

    { // init
        float4 z = make_float4(0.f, 0.f, 0.f, 0.f);
        for (int i = tid; i < 8192; i += 1024) ((float4*)acc)[i] = z;
        if (tid < CCLS) cnts[tid] = 0;
        int v = 0;
        if (tid < 64) v = ((const int*)mask)[tid];
        unsigned long long bal = __ballot((unsigned)v > 1u);
        if (tid == 0) sIsBool = (bal != 0ull);
    }
    __syncthreads();
    const bool isBool = (sIsBool != 0);

    const int wave = tid >> 6, lane = tid & 63;
    const int s0 = b * 1024 + wave * 64;
    const float2* lg2 = (const float2*)logits;   // 64 float2 per row
    const float4* im4 = (const float4*)img;      // 64 float4 per row

    int myGate = isBool ? (int)((const unsigned char*)mask)[s0 + lane]
                        : ((const int*)mask)[s0 + lane];
    unsigned long long gm = __ballot(myGate != 0);

    // 2-deep pipeline over gated samples
    int tn = -1; float2 lgn; float4 vn;
    if (gm) {
        tn = (int)(__ffsll((long long)gm) - 1); gm &= gm - 1;
        lgn = lg2[(size_t)(s0 + tn) * 64 + lane];
        vn  = im4[(size_t)(s0 + tn) * 64 + lane];
    }
    while (tn >= 0) {
        float2 lg = lgn; float4 v = vn;
        tn = -1;
        if (gm) {
            tn = (int)(__ffsll((long long)gm) - 1); gm &= gm - 1;
            lgn = lg2[(size_t)(s0 + tn) * 64 + lane];
            vn  = im4[(size_t)(s0 + tn) * 64 + lane];
        }
        // wave-wide argmax of 128 logits (lane holds dims 2L, 2L+1)
        float m = lg.x; int id = 2 * lane;
        if (lg.y > m) { m = lg.y; id = 2 * lane + 1; }
        #pragma unroll
        for (int off = 1; off < 64; off <<= 1) {
            float om = __shfl_xor(m, off);
            int   oi = __shfl_xor(id, off);
            if (om > m || (om == m && oi < id)) { m = om; id = oi; }
        }
        // accumulate (permuted layout: dim 4L+j at slot j*64+L, conflict-free)
        atomicAdd(&acc[id][lane],       v.x);
        atomicAdd(&acc[id][64 + lane],  v.y);
        atomicAdd(&acc[id][128 + lane], v.z);
        atomicAdd(&acc[id][192 + lane], v.w);
        if (lane == 0) atomicAdd(&cnts[id], 1);
    }
    __syncthreads();

    const float* accF = &acc[0][0];
    if (nSlab == 256) {
        float4* pp = (float4*)((float*)(ws + OFF_BIG) + (size_t)b * SLAB_FLOATS);
        for (int i = tid; i < 8192; i += 1024) pp[i] = ((const float4*)accF)[i];
    } else {
        float* slab = (float*)(ws + OFF_BIG) + (size_t)(b % nSlab) * SLAB_FLOATS;
        for (int i = tid; i < SLAB_FLOATS; i += 1024)
            if (accF[i] != 0.f) unsafeAtomicAdd(&slab[i], accF[i]);
    }
    if (tid < CCLS && cnts[tid]) atomicAdd(&((int*)(ws + OFF_COUNTS))[tid], cnts[tid]);
}

// ---------------------------------------------------------------------------
// KB: reduce slabs -> class means Mraw (un-permuting dim layout)
// ---------------------------------------------------------------------------
extern "C" __global__ __launch_bounds__(128)
void kb_means(char* __restrict__ ws, int nSlab)
{
    const int idx = blockIdx.x * 128 + threadIdx.x;   // [0, 32768)
    const float* p = (const float*)(ws + OFF_BIG) + idx;
    float a = 0.f;
    for (int pb = 0; pb < nSlab; ++pb) a += p[(size_t)pb * SLAB_FLOATS];
    const int c = idx >> 8, slot = idx & 255;
    const int* counts = (const int*)(ws + OFF_COUNTS);
    const int d = 4 * (slot & 63) + (slot >> 6);      // unpermute
    float cf = fmaxf((float)counts[c], 1.0f);
    ((float*)(ws + OFF_MRAW))[c * 256 + d] = a / cf;
}

// ---------------------------------------------------------------------------
// KC: standalone Gauss-Jordan inversion of G (SPD) -> W. 1 block x 256 thr.
// ---------------------------------------------------------------------------
extern "C" __global__ __launch_bounds__(256)
void kc_inv(char* __restrict__ ws)
{
    __shared__ float prA[128], prB[128], pcA[128], pcB[128];
    const int tid = threadIdx.x;
    const float* G = (const float*)(ws + OFF_G);
    float* W = (float*)(ws + OFF_W);
    float gg[8][8];
    const int r0 = 8 * (tid >> 4), c0 = 8 * (tid & 15);
    #pragma unroll
    for (int ii = 0; ii < 8; ++ii) {
        *(float4*)&gg[ii][0] = *(const float4*)&G[(r0 + ii) * 128 + c0];
        *(float4*)&gg[ii][4] = *(const float4*)&G[(r0 + ii) * 128 + c0 + 4];
    }
    if (r0 == 0) {
        #pragma unroll
        for (int j = 0; j < 8; ++j) prA[c0 + j] = gg[0][j];
    }
    if (c0 == 0) {
        #pragma unroll
        for (int i = 0; i < 8; ++i) pcA[r0 + i] = gg[i][0];
    }
    __syncthreads();
    for (int k = 0; k < 128; ++k) {
        const float* pr = (k & 1) ? prB : prA;
        const float* pc = (k & 1) ? pcB : pcA;
        float rinv = 1.0f / pr[k];
        float rf[8], fc[8];
        #pragma unroll
        for (int j = 0; j < 8; ++j) { rf[j] = pr[c0 + j] * rinv; if (c0 + j == k) rf[j] = rinv; }
        #pragma unroll
        for (int i = 0; i < 8; ++i) fc[i] = pc[r0 + i];
        #pragma unroll
        for (int i = 0; i < 8; ++i) {
            if (r0 + i == k) {
                #pragma unroll
                for (int j = 0; j < 8; ++j) gg[i][j] = rf[j];
            } else {
                float f = fc[i];
                #pragma unroll
                for (int j = 0; j < 8; ++j) {
                    float base = (c0 + j == k) ? 0.0f : gg[i][j];
                    gg[i][j] = base - f * rf[j];
                }
            }
        }
        int kn = k + 1;
        if (kn < 128) {
            float* prn = (kn & 1) ? prB : prA;
            float* pcn = (kn & 1) ? pcB : pcA;
            if (kn >= r0 && kn < r0 + 8) {
                #pragma unroll
                for (int j = 0; j < 8; ++j) prn[c0 + j] = gg[kn - r0][j];
            }
            if (kn >= c0 && kn < c0 + 8) {
                #pragma unroll
                for (int i = 0; i < 8; ++i) pcn[r0 + i] = gg[i][kn - c0];
            }
        }
        __syncthreads();
    }
    #pragma unroll
    for (int ii = 0; ii < 8; ++ii) {
        *(float4*)&W[(r0 + ii) * 128 + c0]     = *(float4*)&gg[ii][0];
        *(float4*)&W[(r0 + ii) * 128 + c0 + 4] = *(float4*)&gg[ii][4];
    }
}

// K4: B = Mraw @ T^T  (128x128)
extern "C" __global__ __launch_bounds__(128)
void k4_B(char* __restrict__ ws)
{
    __shared__ float mr[256];
    const int c = blockIdx.x, j = threadIdx.x;
    const float* Mraw = (const float*)(ws + OFF_MRAW);
    const float* Tt = (const float*)(ws + OFF_TT);
    mr[j] = Mraw[c * 256 + j]; mr[j + 128] = Mraw[c * 256 + 128 + j];
    __syncthreads();
    float a = 0.f;
    #pragma unroll 8
    for (int d = 0; d < 256; ++d) a += mr[d] * Tt[d * 128 + j];
    ((float*)(ws + OFF_B))[c * 128 + j] = a;
}

// K5: Zt = (B @ W)^T = W @ B^T   (W symmetric)
extern "C" __global__ __launch_bounds__(128)
void k5_Z(char* __restrict__ ws)
{
    __shared__ float bc[128];
    const int c = blockIdx.x, j = threadIdx.x;
    const float* B = (const float*)(ws + OFF_B);
    const float* W = (const float*)(ws + OFF_W);
    bc[j] = B[c * 128 + j];
    __syncthreads();
    float a = 0.f;
    #pragma unroll 8
    for (int k = 0; k < 128; ++k) a += bc[k] * W[k * 128 + j];
    ((float*)(ws + OFF_ZT))[j * 128 + c] = a;
}

// K6: M = B @ Zt = B W B^T
extern "C" __global__ __launch_bounds__(128)
void k6_M(char* __restrict__ ws)
{
    __shared__ float bc[128];
    const int c = blockIdx.x, j = threadIdx.x;
    const float* B = (const float*)(ws + OFF_B);
    const float* Zt = (const float*)(ws + OFF_ZT);
    bc[j] = B[c * 128 + j];
    __syncthreads();
    float a = 0.f;
    #pragma unroll 8
    for (int k = 0; k < 128; ++k) a += bc[k] * Zt[k * 128 + j];
    ((float*)(ws + OFF_M))[c * 128 + j] = a;
}

// K7: loss
extern "C" __global__ __launch_bounds__(256)
void k7_loss(char* __restrict__ ws, float* __restrict__ out)
{
    __shared__ float norms[128];
    __shared__ int pres[128];
    __shared__ float wsum[4];
    const int tid = threadIdx.x;
    const float* M = (const float*)(ws + OFF_M);
    const int* counts = (const int*)(ws + OFF_COUNTS);
    if (tid < 128) {
        int p = counts[tid] > 0;
        pres[tid] = p;
        norms[tid] = sqrtf(p ? M[tid * 129] : 1.0f);
    }
    __syncthreads();
    float ls = 0.f;
    for (int idx = tid; idx < 16384; idx += 256) {
        int c = idx >> 7, j = idx & 127;
        if (c != j && pres[c] && pres[j])
            ls += 1.0f - M[idx] / ((norms[c] + EPSF) * (norms[j] + EPSF));
    }
    #pragma unroll
    for (int off = 32; off > 0; off >>= 1) ls += __shfl_down(ls, off);
    if ((tid & 63) == 0) wsum[tid >> 6] = ls;
    __syncthreads();
    if (tid == 0) {
        int np = 0;
        for (int c = 0; c < 128; ++c) np += pres[c];
        float tot = wsum[0] + wsum[1] + wsum[2] + wsum[3];
        out[0] = (np >= 2) ? tot : 0.0f;
    }
}

// ---------------------------------------------------------------------------
extern "C" void kernel_launch(void* const* d_in, const int* in_sizes, int n_in,
                              void* d_out, int out_size, void* d_ws, size_t ws_size,
                              hipStream_t stream)
{
    const float* logits = (const float*)d_in[0];
    const float* img    = (const float*)d_in[1];
    const float* T      = (const float*)d_in[2];
    const void*  mask   = d_in[3];
    char* ws = (char*)d_ws;

    size_t avail = (ws_size > (size_t)OFF_BIG) ? ws_size - OFF_BIG : 0;
    int nSlab = (int)(avail / (SLAB_FLOATS * 4));
    if (nSlab > 256) nSlab = 256;
    if (nSlab < 1) nSlab = 1;

    hipMemsetAsync(ws + OFF_COUNTS, 0, 512, stream);
    if (nSlab < 256)
        hipMemsetAsync(ws + OFF_BIG, 0, (size_t)nSlab * SLAB_FLOATS * 4, stream);

    kg_gram<<<4, 1024, 0, stream>>>(T, ws);
    ka_fused<<<256, 1024, 0, stream>>>(logits, img, mask, ws, nSlab);
    kb_means<<<256, 128, 0, stream>>>(ws, nSlab);
    kc_inv<<<1, 256, 0, stream>>>(ws);
    k4_B<<<128, 128, 0, stream>>>(ws);
    k5_Z<<<128, 128, 0, stream>>>(ws);
    k6_M<<<128, 128, 0, stream>>>(ws);
    k7_loss<<<1, 256, 0, stream>>>(ws, (float*)d_out);
}

// Round 4
// 488.614 us; speedup vs baseline: 1.8238x; 1.8238x over previous
//
#include <hip/hip_runtime.h>

// Problem constants
#define NSAMP 262144
#define CCLS 128
#define DDIM 256
#define EPSF 1e-8f

// ws byte offsets (16B-aligned where vector-accessed)
#define OFF_COUNTS   0u          // 128 * u32
#define OFF_G        2048u       // 128x128 f32
#define OFF_W        67584u      // 128x128 f32 (G^-1)
#define OFF_TT       133120u     // 256x128 f32 (T transposed)
#define OFF_MRAW     264192u     // 128x256 f32 (class means, unprojected)
#define OFF_B        395264u     // 128x128 f32 (Mraw @ T^T)
#define OFF_ZT       460800u     // 128x128 f32 (W @ B^T)
#define OFF_M        526336u     // 128x128 f32 (B W B^T)
#define OFF_BIG      1644288u    // partial slabs, 32768 f32 each
#define SLAB_FLOATS  32768

// ---------------------------------------------------------------------------
// KG: 4 blocks. Block g computes rows [32g,32g+32) of G = T*T^T and writes
//     T^T chunk g.
// ---------------------------------------------------------------------------
extern "C" __global__ __launch_bounds__(1024)
void kg_gram(const float* __restrict__ T, char* __restrict__ ws)
{
    __shared__ float Tl[64][132];
    const int g = blockIdx.x, tid = threadIdx.x;
    float* Tt = (float*)(ws + OFF_TT);
    float* G  = (float*)(ws + OFF_G);
    float a0[8], a1[8];
    #pragma unroll
    for (int j = 0; j < 8; ++j) { a0[j] = 0.f; a1[j] = 0.f; }
    const int Lr = 2 * (tid >> 4);
    const int c0 = 8 * (tid & 15);
    for (int ch = 0; ch < 4; ++ch) {
        for (int i = tid; i < 8192; i += 1024) {
            int cc = i >> 6, dd = i & 63;
            Tl[dd][cc] = T[cc * 256 + ch * 64 + dd];
        }
        __syncthreads();
        if (g == ch) {
            for (int i = tid; i < 8192; i += 1024) {
                int c2 = i & 127, d2 = i >> 7;
                Tt[(ch * 64 + d2) * 128 + c2] = Tl[d2][c2];
            }
        }
        if (tid < 256) {
            for (int dd = 0; dd < 64; ++dd) {
                float r0 = Tl[dd][32 * g + Lr];
                float r1 = Tl[dd][32 * g + Lr + 1];
                float cv[8];
                *(float4*)&cv[0] = *(const float4*)&Tl[dd][c0];
                *(float4*)&cv[4] = *(const float4*)&Tl[dd][c0 + 4];
                #pragma unroll
                for (int j = 0; j < 8; ++j) { a0[j] += r0 * cv[j]; a1[j] += r1 * cv[j]; }
            }
        }
        __syncthreads();
    }
    if (tid < 256) {
        int gr = 32 * g + Lr;
        *(float4*)&G[gr * 128 + c0]           = make_float4(a0[0], a0[1], a0[2], a0[3]);
        *(float4*)&G[gr * 128 + c0 + 4]       = make_float4(a0[4], a0[5], a0[6], a0[7]);
        *(float4*)&G[(gr + 1) * 128 + c0]     = make_float4(a1[0], a1[1], a1[2], a1[3]);
        *(float4*)&G[(gr + 1) * 128 + c0 + 4] = make_float4(a1[4], a1[5], a1[6], a1[7]);
    }
}

// ---------------------------------------------------------------------------
// KA: fused argmax + gated segment-sum. 256 blocks x 1024 threads.
// ---------------------------------------------------------------------------
extern "C" __global__ __launch_bounds__(1024)
void ka_fused(const float* __restrict__ logits, const float* __restrict__ img,
              const void* __restrict__ mask, char* __restrict__ ws, int nSlab)
{
    __shared__ float acc[CCLS][DDIM];   // 128 KB
    __shared__ int cnts[CCLS];
    __shared__ int sIsBool;
    const int b = blockIdx.x, tid = threadIdx.x;

    { // init
        float4 z = make_float4(0.f, 0.f, 0.f, 0.f);
        for (int i = tid; i < 8192; i += 1024) ((float4*)acc)[i] = z;
        if (tid < CCLS) cnts[tid] = 0;
        int v = 0;
        if (tid < 64) v = ((const int*)mask)[tid];
        unsigned long long bal = __ballot((unsigned)v > 1u);
        if (tid == 0) sIsBool = (bal != 0ull);
    }
    __syncthreads();
    const bool isBool = (sIsBool != 0);

    const int wave = tid >> 6, lane = tid & 63;
    const int s0 = b * 1024 + wave * 64;
    const float2* lg2 = (const float2*)logits;   // 64 float2 per row
    const float4* im4 = (const float4*)img;      // 64 float4 per row

    int myGate = isBool ? (int)((const unsigned char*)mask)[s0 + lane]
                        : ((const int*)mask)[s0 + lane];
    unsigned long long gm = __ballot(myGate != 0);

    // 2-deep pipeline over gated samples
    int tn = -1; float2 lgn; float4 vn;
    if (gm) {
        tn = (int)(__ffsll((long long)gm) - 1); gm &= gm - 1;
        lgn = lg2[(size_t)(s0 + tn) * 64 + lane];
        vn  = im4[(size_t)(s0 + tn) * 64 + lane];
    }
    while (tn >= 0) {
        float2 lg = lgn; float4 v = vn;
        tn = -1;
        if (gm) {
            tn = (int)(__ffsll((long long)gm) - 1); gm &= gm - 1;
            lgn = lg2[(size_t)(s0 + tn) * 64 + lane];
            vn  = im4[(size_t)(s0 + tn) * 64 + lane];
        }
        // wave-wide argmax of 128 logits (lane holds dims 2L, 2L+1)
        float m = lg.x; int id = 2 * lane;
        if (lg.y > m) { m = lg.y; id = 2 * lane + 1; }
        #pragma unroll
        for (int off = 1; off < 64; off <<= 1) {
            float om = __shfl_xor(m, off);
            int   oi = __shfl_xor(id, off);
            if (om > m || (om == m && oi < id)) { m = om; id = oi; }
        }
        // accumulate (permuted layout: dim 4L+j at slot j*64+L, conflict-free)
        atomicAdd(&acc[id][lane],       v.x);
        atomicAdd(&acc[id][64 + lane],  v.y);
        atomicAdd(&acc[id][128 + lane], v.z);
        atomicAdd(&acc[id][192 + lane], v.w);
        if (lane == 0) atomicAdd(&cnts[id], 1);
    }
    __syncthreads();

    const float* accF = &acc[0][0];
    if (nSlab == 256) {
        float4* pp = (float4*)((float*)(ws + OFF_BIG) + (size_t)b * SLAB_FLOATS);
        for (int i = tid; i < 8192; i += 1024) pp[i] = ((const float4*)accF)[i];
    } else {
        float* slab = (float*)(ws + OFF_BIG) + (size_t)(b % nSlab) * SLAB_FLOATS;
        for (int i = tid; i < SLAB_FLOATS; i += 1024)
            if (accF[i] != 0.f) unsafeAtomicAdd(&slab[i], accF[i]);
    }
    if (tid < CCLS && cnts[tid]) atomicAdd(&((int*)(ws + OFF_COUNTS))[tid], cnts[tid]);
}

// ---------------------------------------------------------------------------
// KB: reduce slabs -> class means Mraw (un-permuting dim layout)
// ---------------------------------------------------------------------------
extern "C" __global__ __launch_bounds__(128)
void kb_means(char* __restrict__ ws, int nSlab)
{
    const int idx = blockIdx.x * 128 + threadIdx.x;   // [0, 32768)
    const float* p = (const float*)(ws + OFF_BIG) + idx;
    float a = 0.f;
    for (int pb = 0; pb < nSlab; ++pb) a += p[(size_t)pb * SLAB_FLOATS];
    const int c = idx >> 8, slot = idx & 255;
    const int* counts = (const int*)(ws + OFF_COUNTS);
    const int d = 4 * (slot & 63) + (slot >> 6);      // unpermute
    float cf = fmaxf((float)counts[c], 1.0f);
    ((float*)(ws + OFF_MRAW))[c * 256 + d] = a / cf;
}

// ---------------------------------------------------------------------------
// KC: Gauss-Jordan inversion of G (SPD) -> W. 1 block x 256 threads.
//     ALL gg[][] indices compile-time (rule #20: runtime-indexed ext arrays
//     go to scratch -> was 537us at VGPR=32; static indexing keeps gg in VGPRs).
// ---------------------------------------------------------------------------
extern "C" __global__ __launch_bounds__(256)
void kc_inv(char* __restrict__ ws)
{
    __shared__ float prA[128], prB[128], pcA[128], pcB[128];
    const int tid = threadIdx.x;
    const float* G = (const float*)(ws + OFF_G);
    float* W = (float*)(ws + OFF_W);
    float gg[8][8];
    const int r0 = 8 * (tid >> 4), c0 = 8 * (tid & 15);
    #pragma unroll
    for (int ii = 0; ii < 8; ++ii) {
        *(float4*)&gg[ii][0] = *(const float4*)&G[(r0 + ii) * 128 + c0];
        *(float4*)&gg[ii][4] = *(const float4*)&G[(r0 + ii) * 128 + c0 + 4];
    }
    if (r0 == 0) {
        #pragma unroll
        for (int j = 0; j < 8; ++j) prA[c0 + j] = gg[0][j];
    }
    if (c0 == 0) {
        #pragma unroll
        for (int i = 0; i < 8; ++i) pcA[r0 + i] = gg[i][0];
    }
    __syncthreads();
    for (int k = 0; k < 128; ++k) {
        const float* pr = (k & 1) ? prB : prA;
        const float* pc = (k & 1) ? pcB : pcA;
        float rinv = 1.0f / pr[k];
        float rf[8], fc[8];
        #pragma unroll
        for (int j = 0; j < 8; ++j) { rf[j] = pr[c0 + j] * rinv; if (c0 + j == k) rf[j] = rinv; }
        #pragma unroll
        for (int i = 0; i < 8; ++i) fc[i] = pc[r0 + i];
        #pragma unroll
        for (int i = 0; i < 8; ++i) {
            if (r0 + i == k) {
                #pragma unroll
                for (int j = 0; j < 8; ++j) gg[i][j] = rf[j];
            } else {
                float f = fc[i];
                #pragma unroll
                for (int j = 0; j < 8; ++j) {
                    float base = (c0 + j == k) ? 0.0f : gg[i][j];
                    gg[i][j] = base - f * rf[j];
                }
            }
        }
        const int kn = k + 1;
        if (kn < 128) {
            float* prn = (kn & 1) ? prB : prA;
            float* pcn = (kn & 1) ? pcB : pcA;
            // compile-time-indexed extraction of next pivot row/col
            #pragma unroll
            for (int ii = 0; ii < 8; ++ii) {
                if (r0 + ii == kn) {
                    #pragma unroll
                    for (int j = 0; j < 8; ++j) prn[c0 + j] = gg[ii][j];
                }
            }
            #pragma unroll
            for (int jj = 0; jj < 8; ++jj) {
                if (c0 + jj == kn) {
                    #pragma unroll
                    for (int i = 0; i < 8; ++i) pcn[r0 + i] = gg[i][jj];
                }
            }
        }
        __syncthreads();
    }
    #pragma unroll
    for (int ii = 0; ii < 8; ++ii) {
        *(float4*)&W[(r0 + ii) * 128 + c0]     = *(float4*)&gg[ii][0];
        *(float4*)&W[(r0 + ii) * 128 + c0 + 4] = *(float4*)&gg[ii][4];
    }
}

// K4: B = Mraw @ T^T  (128x128)
extern "C" __global__ __launch_bounds__(128)
void k4_B(char* __restrict__ ws)
{
    __shared__ float mr[256];
    const int c = blockIdx.x, j = threadIdx.x;
    const float* Mraw = (const float*)(ws + OFF_MRAW);
    const float* Tt = (const float*)(ws + OFF_TT);
    mr[j] = Mraw[c * 256 + j]; mr[j + 128] = Mraw[c * 256 + 128 + j];
    __syncthreads();
    float a = 0.f;
    #pragma unroll 8
    for (int d = 0; d < 256; ++d) a += mr[d] * Tt[d * 128 + j];
    ((float*)(ws + OFF_B))[c * 128 + j] = a;
}

// K5: Zt = (B @ W)^T = W @ B^T   (W symmetric)
extern "C" __global__ __launch_bounds__(128)
void k5_Z(char* __restrict__ ws)
{
    __shared__ float bc[128];
    const int c = blockIdx.x, j = threadIdx.x;
    const float* B = (const float*)(ws + OFF_B);
    const float* W = (const float*)(ws + OFF_W);
    bc[j] = B[c * 128 + j];
    __syncthreads();
    float a = 0.f;
    #pragma unroll 8
    for (int k = 0; k < 128; ++k) a += bc[k] * W[k * 128 + j];
    ((float*)(ws + OFF_ZT))[j * 128 + c] = a;
}

// K6: M = B @ Zt = B W B^T
extern "C" __global__ __launch_bounds__(128)
void k6_M(char* __restrict__ ws)
{
    __shared__ float bc[128];
    const int c = blockIdx.x, j = threadIdx.x;
    const float* B = (const float*)(ws + OFF_B);
    const float* Zt = (const float*)(ws + OFF_ZT);
    bc[j] = B[c * 128 + j];
    __syncthreads();
    float a = 0.f;
    #pragma unroll 8
    for (int k = 0; k < 128; ++k) a += bc[k] * Zt[k * 128 + j];
    ((float*)(ws + OFF_M))[c * 128 + j] = a;
}

// K7: loss
extern "C" __global__ __launch_bounds__(256)
void k7_loss(char* __restrict__ ws, float* __restrict__ out)
{
    __shared__ float norms[128];
    __shared__ int pres[128];
    __shared__ float wsum[4];
    const int tid = threadIdx.x;
    const float* M = (const float*)(ws + OFF_M);
    const int* counts = (const int*)(ws + OFF_COUNTS);
    if (tid < 128) {
        int p = counts[tid] > 0;
        pres[tid] = p;
        norms[tid] = sqrtf(p ? M[tid * 129] : 1.0f);
    }
    __syncthreads();
    float ls = 0.f;
    for (int idx = tid; idx < 16384; idx += 256) {
        int c = idx >> 7, j = idx & 127;
        if (c != j && pres[c] && pres[j])
            ls += 1.0f - M[idx] / ((norms[c] + EPSF) * (norms[j] + EPSF));
    }
    #pragma unroll
    for (int off = 32; off > 0; off >>= 1) ls += __shfl_down(ls, off);
    if ((tid & 63) == 0) wsum[tid >> 6] = ls;
    __syncthreads();
    if (tid == 0) {
        int np = 0;
        for (int c = 0; c < 128; ++c) np += pres[c];
        float tot = wsum[0] + wsum[1] + wsum[2] + wsum[3];
        out[0] = (np >= 2) ? tot : 0.0f;
    }
}

// ---------------------------------------------------------------------------
extern "C" void kernel_launch(void* const* d_in, const int* in_sizes, int n_in,
                              void* d_out, int out_size, void* d_ws, size_t ws_size,
                              hipStream_t stream)
{
    const float* logits = (const float*)d_in[0];
    const float* img    = (const float*)d_in[1];
    const float* T      = (const float*)d_in[2];
    const void*  mask   = d_in[3];
    char* ws = (char*)d_ws;

    size_t avail = (ws_size > (size_t)OFF_BIG) ? ws_size - OFF_BIG : 0;
    int nSlab = (int)(avail / (SLAB_FLOATS * 4));
    if (nSlab > 256) nSlab = 256;
    if (nSlab < 1) nSlab = 1;

    hipMemsetAsync(ws + OFF_COUNTS, 0, 512, stream);
    if (nSlab < 256)
        hipMemsetAsync(ws + OFF_BIG, 0, (size_t)nSlab * SLAB_FLOATS * 4, stream);

    kg_gram<<<4, 1024, 0, stream>>>(T, ws);
    ka_fused<<<256, 1024, 0, stream>>>(logits, img, mask, ws, nSlab);
    kb_means<<<256, 128, 0, stream>>>(ws, nSlab);
    kc_inv<<<1, 256, 0, stream>>>(ws);
    k4_B<<<128, 128, 0, stream>>>(ws);
    k5_Z<<<128, 128, 0, stream>>>(ws);
    k6_M<<<128, 128, 0, stream>>>(ws);
    k7_loss<<<1, 256, 0, stream>>>(ws, (float*)d_out);
}